// Round 6
// baseline (241.404 us; speedup 1.0000x reference)
//
#include <hip/hip_runtime.h>

// out[b,o] = x[b,:] @ W_lin[:,o] + x[b] @ W_nl[o] @ x[b]
// Symmetry-folded GEMM: each unordered pair {i,j} used once with
// W'[o,{i,j}] = Wnl[o,i,j] + Wnl[o,j,i]  ->  K = 496 + 16 + 32 + 32... = 560
// organized as 35 K=16 steps of v_mfma_f32_32x32x16_bf16:
//   steps 0..29 : diagonals d=1..15, blk=0/1: pairs (i, (i+d)&31), i=blk*16..+16
//   step  30    : d=16, i in [0,16)
//   steps 31,32 : squares x_i^2 (diag of Wnl), blk=0/1
//   steps 33,34 : linear part (Wlin), blk=0/1
// Lane-half trick: s[k] = x[m, (k + 8*hf) & 31] (row loaded pre-rotated from
// global, free), so A-element j of step (d,blk) = s[blk+j] * s[(blk+j+d)&31]
// -- ALL register indices compile-time static: no cndmask, no spill.
// Regs ~75 (s 32 + acc 16 + temps) << 128; LDS 35 KiB -> 4 blocks/CU.

typedef __attribute__((ext_vector_type(8)))  __bf16 bf16x8;
typedef __attribute__((ext_vector_type(4)))  float  floatx4;
typedef __attribute__((ext_vector_type(16))) float  floatx16;

#define NB    524288
#define NT    (NB / 32)      // 16384 32-row tiles
#define NBLK  1024
#define NSTR  (NBLK * 4)     // 4096 wave streams
#define TPW   (NT / NSTR)    // 4 tiles per wave

__global__ __launch_bounds__(256)
void nnode_kernel(const float* __restrict__ x, const float* __restrict__ Wlin,
                  const float* __restrict__ Wnl, float* __restrict__ out) {
    __shared__ bf16x8 wlds[35 * 64];   // 35 KiB, B-fragments in MFMA order

    const int tid = threadIdx.x;

    // ---- one-time staging of folded weights into fragment order ----
    // entry (step, lane): element j <-> k_local = (lane>>5)*8 + j, n = lane&31
    for (int r = tid; r < 35 * 64; r += 256) {
        const int step = r >> 6;
        const int ln   = r & 63;
        const int o    = ln & 31;
        const int hf   = ln >> 5;
        const float* Wo = Wnl + (size_t)o * 1024;
        bf16x8 v;
        if (step < 30) {                    // pairs, d = 1..15
            const int d   = 1 + (step >> 1);
            const int blk = (step & 1) * 16;
            #pragma unroll
            for (int j = 0; j < 8; ++j) {
                const int i  = blk + hf * 8 + j;
                const int jj = (i + d) & 31;
                v[j] = (__bf16)(Wo[i * 32 + jj] + Wo[jj * 32 + i]);
            }
        } else if (step == 30) {            // d = 16, i in [0,16)
            #pragma unroll
            for (int j = 0; j < 8; ++j) {
                const int i = hf * 8 + j;
                v[j] = (__bf16)(Wo[i * 32 + (i + 16)] + Wo[(i + 16) * 32 + i]);
            }
        } else if (step < 33) {             // squares
            const int blk = (step - 31) * 16;
            #pragma unroll
            for (int j = 0; j < 8; ++j) {
                const int i = blk + hf * 8 + j;
                v[j] = (__bf16)Wo[i * 32 + i];
            }
        } else {                            // linear
            const int blk = (step - 33) * 16;
            #pragma unroll
            for (int j = 0; j < 8; ++j) {
                const int i = blk + hf * 8 + j;
                v[j] = (__bf16)Wlin[(size_t)i * 32 + o];
            }
        }
        wlds[r] = v;
    }
    __syncthreads();

    const int wave = tid >> 6;
    const int lane = tid & 63;
    const int hf   = lane >> 5;
    const int m    = lane & 31;     // A row within tile; also C/D col (=o)

    const int stream = blockIdx.x * 4 + wave;

    #pragma unroll 1
    for (int t = 0; t < TPW; ++t) {
        const int tile = stream * TPW + t;
        const float* xr = x + ((size_t)tile * 32 + m) * 32;

        // s[k] = x[m, (k + 8*hf) & 31] : row loaded pre-rotated by 8*hf
        float s[32];
        #pragma unroll
        for (int c = 0; c < 8; ++c) {
            const int off = (c * 4 + 8 * hf) & 31;   // 4-aligned, no straddle
            floatx4 v = *(const floatx4*)(xr + off);
            s[c * 4 + 0] = v[0]; s[c * 4 + 1] = v[1];
            s[c * 4 + 2] = v[2]; s[c * 4 + 3] = v[3];
        }

        floatx16 acc;
        #pragma unroll
        for (int r = 0; r < 16; ++r) acc[r] = 0.0f;

        // steps 0..29: d = 1..15, blk = 0/16
        #pragma unroll
        for (int st = 0; st < 30; ++st) {
            const int d   = 1 + (st >> 1);
            const int blk = (st & 1) * 16;
            bf16x8 bf = wlds[st * 64 + lane];
            bf16x8 af;
            #pragma unroll
            for (int j = 0; j < 8; ++j)
                af[j] = (__bf16)(s[blk + j] * s[(blk + j + d) & 31]);
            acc = __builtin_amdgcn_mfma_f32_32x32x16_bf16(af, bf, acc, 0, 0, 0);
        }
        // step 30: d = 16
        {
            bf16x8 bf = wlds[30 * 64 + lane];
            bf16x8 af;
            #pragma unroll
            for (int j = 0; j < 8; ++j)
                af[j] = (__bf16)(s[j] * s[(j + 16) & 31]);
            acc = __builtin_amdgcn_mfma_f32_32x32x16_bf16(af, bf, acc, 0, 0, 0);
        }
        // steps 31,32: squares
        #pragma unroll
        for (int b2 = 0; b2 < 2; ++b2) {
            bf16x8 bf = wlds[(31 + b2) * 64 + lane];
            bf16x8 af;
            #pragma unroll
            for (int j = 0; j < 8; ++j) {
                const float v = s[b2 * 16 + j];
                af[j] = (__bf16)(v * v);
            }
            acc = __builtin_amdgcn_mfma_f32_32x32x16_bf16(af, bf, acc, 0, 0, 0);
        }
        // steps 33,34: linear (A element = x itself)
        #pragma unroll
        for (int b2 = 0; b2 < 2; ++b2) {
            bf16x8 bf = wlds[(33 + b2) * 64 + lane];
            bf16x8 af;
            #pragma unroll
            for (int j = 0; j < 8; ++j)
                af[j] = (__bf16)s[b2 * 16 + j];
            acc = __builtin_amdgcn_mfma_f32_32x32x16_bf16(af, bf, acc, 0, 0, 0);
        }

        // store: out[tile*32 + (r&3)+8*(r>>2)+4*hf, o = m]
        float* ob = out + ((size_t)tile * 32 + 4 * hf) * 32 + m;
        #pragma unroll
        for (int r = 0; r < 16; ++r) {
            const int rowr = (r & 3) + 8 * (r >> 2);
            ob[(size_t)rowr * 32] = acc[r];
        }
    }
}

extern "C" void kernel_launch(void* const* d_in, const int* in_sizes, int n_in,
                              void* d_out, int out_size, void* d_ws, size_t ws_size,
                              hipStream_t stream) {
    const float* x    = (const float*)d_in[0];
    const float* Wlin = (const float*)d_in[1];
    const float* Wnl  = (const float*)d_in[2];
    float* out        = (float*)d_out;
    nnode_kernel<<<dim3(NBLK), dim3(256), 0, stream>>>(x, Wlin, Wnl, out);
}